// Round 10
// baseline (222.009 us; speedup 1.0000x reference)
//
#include <hip/hip_runtime.h>

// MaskedGNN MI355X — round 10: r9 chain with (a) layer score phase reading
// hq/We2 as wave-uniform SCALAR loads from global (no LDS staging, no first
// barrier; s_load via readfirstlane-pinned base), (b) dec 256-thr split-K.
// 6 launches: prep -> enc+qkv0 -> layer x3 -> dec.
// H=128, N=64, B=128, L=3, F=7, E=64.
// MFMA 16x16x32 bf16 fragments:
//   A-frag: lane holds A[m=lane&15][k=(lane>>4)*8+j]
//   B-frag: lane holds B[k=(lane>>4)*8+j][n=lane&15]
//   C/D:    col=lane&15, row=(lane>>4)*4+reg

constexpr float EPS = 1e-5f;
constexpr float NEGI = -1e9f;

typedef __bf16 bf16x8 __attribute__((ext_vector_type(8)));
typedef float floatx4 __attribute__((ext_vector_type(4)));
typedef _Float16 h2 __attribute__((ext_vector_type(2)));
union U32H2 { unsigned int u; h2 h; };

__device__ __forceinline__ unsigned int pkh2(float a, float b) {
  U32H2 u; u.h[0] = (_Float16)a; u.h[1] = (_Float16)b; return u.u;
}
__device__ __forceinline__ float fdot2h(h2 a, h2 b, float c) {
#if __has_builtin(__builtin_amdgcn_fdot2)
  return __builtin_amdgcn_fdot2(a, b, c, false);
#else
  return c + (float)a[0] * (float)b[0] + (float)a[1] * (float)b[1];
#endif
}
__device__ __forceinline__ bf16x8 cvt8(const float* p) {
  float t[8];
  *(float4*)t = *(const float4*)p;
  *(float4*)(t + 4) = *(const float4*)(p + 4);
  bf16x8 r;
#pragma unroll
  for (int j = 0; j < 8; ++j) r[j] = (__bf16)t[j];
  return r;
}

// ---------------------------------------------------------------------------
// prep (verified r3/r6): fold Wqe/Wke, pack weights to MFMA-B, bcat, + w2hg.
__global__ __launch_bounds__(256) void prep_kernel(
    const float* __restrict__ Wq, const float* __restrict__ bq,
    const float* __restrict__ Wk, const float* __restrict__ bk,
    const float* __restrict__ bv, const float* __restrict__ We1,
    const float* __restrict__ be1,
    const float* __restrict__ eW1, const float* __restrict__ eW2,
    const float* __restrict__ Wv, const float* __restrict__ Wo,
    const float* __restrict__ We2,
    __bf16* __restrict__ w1pk, __bf16* __restrict__ w2pk,
    __bf16* __restrict__ wcatpk, __bf16* __restrict__ wopk,
    float* __restrict__ bcat, unsigned int* __restrict__ w2hg) {
  int tid = threadIdx.x, blk = blockIdx.x;
  if (blk < 48) {
    __shared__ float sB[128 * 16];
    __shared__ float sF[128 * 17];
    int jb = blk >> 3, cc = blk & 7;
    int l = jb >> 1, w = jb & 1;
    const float* A = (w ? Wk : Wq) + l * 16384;
    const float* Bm = We1 + l * 32768 + w * 16384;
    int c0 = cc * 16;
    for (int idx = tid; idx < 2048; idx += 256) {
      int m = idx >> 4, c = idx & 15;
      sB[idx] = Bm[m * 128 + c0 + c];
    }
    __syncthreads();
    int r = tid >> 1, c8 = (tid & 1) * 8;
    float acc[8] = {};
    const float4* A4 = (const float4*)(A + r * 128);
#pragma unroll 8
    for (int k4 = 0; k4 < 32; ++k4) {
      float4 a = A4[k4];
      float av[4] = {a.x, a.y, a.z, a.w};
#pragma unroll
      for (int kk = 0; kk < 4; ++kk)
#pragma unroll
        for (int c = 0; c < 8; ++c)
          acc[c] = fmaf(av[kk], sB[(k4 * 4 + kk) * 16 + c8 + c], acc[c]);
    }
    for (int c = 0; c < 8; ++c) sF[r * 17 + c8 + c] = acc[c];
    __syncthreads();
    int kc = tid >> 6, ln = tid & 63;
    int k0 = kc * 32 + (ln >> 4) * 8, n = ln & 15;
    bf16x8 pk;
#pragma unroll
    for (int j = 0; j < 8; ++j) pk[j] = (__bf16)sF[(k0 + j) * 17 + n];
    int ntg = 8 + w * 8 + cc;
    *((bf16x8*)(wcatpk + l * 49152) + (ntg * 4 + kc) * 64 + ln) = pk;
  } else if (blk < 56) {
    int job = blk - 48;
    const float* src;
    __bf16* dst;
    int KCH = 4;
    if (job == 0) { src = eW1; dst = w1pk; KCH = 2; }
    else if (job == 1) { src = eW2; dst = w2pk; }
    else if (job < 5) { int l = job - 2; src = Wv + l * 16384; dst = wcatpk + l * 49152; }
    else { int l = job - 5; src = Wo + l * 16384; dst = wopk + l * 16384; }
    for (int s = tid; s < 8 * KCH * 64; s += 256) {
      int ln = s & 63, q = s >> 6;
      int kc = q % KCH, nt = q / KCH;
      int k0 = kc * 32 + (ln >> 4) * 8, n = nt * 16 + (ln & 15);
      bf16x8 pk;
#pragma unroll
      for (int j = 0; j < 8; ++j) pk[j] = (__bf16)src[(k0 + j) * 128 + n];
      *((bf16x8*)dst + (nt * KCH + kc) * 64 + ln) = pk;
    }
  } else {
    for (int idx = tid; idx < 3 * 384; idx += 256) {
      int l = idx / 384, c = idx % 384;
      float val;
      if (c < 128) {
        val = bv[l * 128 + c];
      } else if (c < 256) {
        int cc2 = c - 128;
        float s = 0.f;
        for (int k = 0; k < 128; ++k) s += bq[l * 128 + k] * We1[l * 32768 + k * 128 + cc2];
        val = s;
      } else {
        int cc2 = c - 256;
        float s = be1[l * 128 + cc2];
        for (int k = 0; k < 128; ++k) s += bk[l * 128 + k] * We1[l * 32768 + 16384 + k * 128 + cc2];
        val = s;
      }
      bcat[l * 384 + c] = val;
    }
    // We2 -> f16-pair packed, for uniform scalar loads in layer
    for (int idx = tid; idx < 192; idx += 256) {
      int l = idx >> 6, c = idx & 63;
      w2hg[l * 64 + c] = pkh2(We2[l * 128 + 2 * c], We2[l * 128 + 2 * c + 1]);
    }
  }
}

// ---------------------------------------------------------------------------
// LN over sT (16 rows x 128, stride 132). mode 0: pack->SX. mode 1: mask+pack.
// mode 2: mask + write back to sT (for pooling).
__device__ __forceinline__ void ln16(float* sT, __bf16* SX, const float* __restrict__ g,
                                     const float* __restrict__ be, float mreg,
                                     int i0, int tid, int mode) {
  int r = tid >> 4, c0 = tid & 15;
  const float* base = sT + r * 132;
  float s = 0.f, q = 0.f;
#pragma unroll
  for (int k = 0; k < 8; ++k) { float v = base[c0 + k * 16]; s += v; q += v * v; }
  s += __shfl_xor(s, 1); s += __shfl_xor(s, 2); s += __shfl_xor(s, 4); s += __shfl_xor(s, 8);
  q += __shfl_xor(q, 1); q += __shfl_xor(q, 2); q += __shfl_xor(q, 4); q += __shfl_xor(q, 8);
  float m = s * (1.f / 128.f);
  float rs = rsqrtf(fmaxf(q * (1.f / 128.f) - m * m, 0.f) + EPS);
  float mk = (mode >= 1) ? __shfl(mreg, i0 + r) : 1.f;
  int c8 = c0 * 8;
  float vals[8];
  *(float4*)vals = *(const float4*)(base + c8);
  *(float4*)(vals + 4) = *(const float4*)(base + c8 + 4);
#pragma unroll
  for (int k = 0; k < 8; ++k)
    vals[k] = fmaxf((vals[k] - m) * rs * g[c8 + k] + be[c8 + k], 0.f) * mk;
  if (mode < 2) {
    bf16x8 pk;
#pragma unroll
    for (int k = 0; k < 8; ++k) pk[k] = (__bf16)vals[k];
    ((bf16x8*)SX)[(c8 >> 5) * 64 + ((c8 >> 3) & 3) * 16 + r] = pk;
  } else {
    *(float4*)(sT + r * 132 + c8) = *(float4*)vals;
    *(float4*)(sT + r * 132 + c8 + 4) = *(float4*)(vals + 4);
  }
}

// qkv tail (verified r9): x(SX packed-A) @ wcat -> v (packed-B via sTv LDS),
// hq/hk via transposed MFMA -> direct global writes.
__device__ __forceinline__ void qkv_tail(
    const __bf16* SX, float* sTv,
    int b, int i0, const __bf16* __restrict__ wc, const float* __restrict__ bc,
    unsigned int* __restrict__ hqg_o, unsigned int* __restrict__ hkT_o,
    __bf16* __restrict__ vpk_o, int tid) {
  int lane = tid & 63, wv = tid >> 6, quad = lane >> 4, cl = lane & 15;
  bf16x8 ax[4];
#pragma unroll
  for (int kc = 0; kc < 4; ++kc) ax[kc] = ((const bf16x8*)SX)[kc * 64 + lane];
  floatx4 acc[6];
#pragma unroll
  for (int n = 0; n < 6; ++n) acc[n] = 0;
#pragma unroll
  for (int kc = 0; kc < 4; ++kc)
#pragma unroll
    for (int n = 0; n < 6; ++n) {
      bf16x8 bw = ((const bf16x8*)wc)[((wv + n * 4) * 4 + kc) * 64 + lane];
      if (n < 2)
        acc[n] = __builtin_amdgcn_mfma_f32_16x16x32_bf16(ax[kc], bw, acc[n], 0, 0, 0);
      else
        acc[n] = __builtin_amdgcn_mfma_f32_16x16x32_bf16(bw, ax[kc], acc[n], 0, 0, 0);
    }
#pragma unroll
  for (int n = 0; n < 6; ++n) {
    int g = wv + n * 4;
    if (n < 2) {                       // v: C-layout -> sTv
      int coll = g * 16 + cl;
      float bb = bc[coll];
#pragma unroll
      for (int r = 0; r < 4; ++r) sTv[(quad * 4 + r) * 132 + coll] = acc[n][r] + bb;
    } else if (n < 4) {                // hq^T: lane holds h=hb..hb+3 of row i=cl
      int hb = (g - 8) * 16 + quad * 4;
      float4 bb4 = *(const float4*)(bc + 128 + hb);
      uint2 o;
      o.x = pkh2(acc[n][0] + bb4.x, acc[n][1] + bb4.y);
      o.y = pkh2(acc[n][2] + bb4.z, acc[n][3] + bb4.w);
      *(uint2*)(hqg_o + (b * 64 + i0 + cl) * 64 + (hb >> 1)) = o;
    } else {                           // hk^T: lane holds h=hb..hb+3 of row j=cl
      int hb = (g - 16) * 16 + quad * 4;
      float4 bb4 = *(const float4*)(bc + 256 + hb);
      hkT_o[b * 4096 + (hb >> 1) * 64 + i0 + cl] =
          pkh2(acc[n][0] + bb4.x, acc[n][1] + bb4.y);
      hkT_o[b * 4096 + ((hb >> 1) + 1) * 64 + i0 + cl] =
          pkh2(acc[n][2] + bb4.z, acc[n][3] + bb4.w);
    }
  }
  __syncthreads();
  {  // v -> packed-B bf16 (r3/r6-verified mapping)
    int nt = tid >> 5, dq = (tid >> 4) & 1, c2 = tid & 15;
    int kcv = i0 >> 5, qg = ((i0 & 31) >> 3) + dq;
    bf16x8 pk;
#pragma unroll
    for (int jj = 0; jj < 8; ++jj) pk[jj] = (__bf16)sTv[(dq * 8 + jj) * 132 + nt * 16 + c2];
    ((bf16x8*)vpk_o)[b * 1024 + (nt * 2 + kcv) * 64 + qg * 16 + c2] = pk;
  }
}

// ---------------------------------------------------------------------------
// encoder + qkv0 (verified r9): 512 blocks = (b, 16-row quarter) x 256 thr.
__global__ __launch_bounds__(256) void enc_qkv_kernel(
    const float* __restrict__ emb, const float* __restrict__ mask,
    const float* __restrict__ eb1, const float* __restrict__ eg1, const float* __restrict__ eB1,
    const float* __restrict__ eb2, const float* __restrict__ eg2, const float* __restrict__ eB2,
    const __bf16* __restrict__ w1pk, const __bf16* __restrict__ w2pk,
    const __bf16* __restrict__ wcat0, const float* __restrict__ bcat0,
    unsigned int* __restrict__ hqg, unsigned int* __restrict__ hkT,
    __bf16* __restrict__ vpk) {
  __shared__ __align__(16) __bf16 SX[2048];
  __shared__ __align__(16) float sTv[16 * 132];
  float* sT = sTv;
  int tid = threadIdx.x, blk = blockIdx.x;
  int lane = tid & 63, wv = tid >> 6, quad = lane >> 4, cl = lane & 15;
  int b = blk >> 2, i0 = (blk & 3) * 16;
  float mreg = mask[b * 64 + lane];

  // E1 (K=64)
  {
    bf16x8 a1[2];
#pragma unroll
    for (int kc = 0; kc < 2; ++kc)
      a1[kc] = cvt8(emb + (b * 64 + i0 + cl) * 64 + kc * 32 + quad * 8);
    floatx4 acc[2];
    acc[0] = 0; acc[1] = 0;
#pragma unroll
    for (int kc = 0; kc < 2; ++kc)
#pragma unroll
      for (int n = 0; n < 2; ++n) {
        bf16x8 bw = ((const bf16x8*)w1pk)[((wv + n * 4) * 2 + kc) * 64 + lane];
        acc[n] = __builtin_amdgcn_mfma_f32_16x16x32_bf16(a1[kc], bw, acc[n], 0, 0, 0);
      }
#pragma unroll
    for (int n = 0; n < 2; ++n) {
      int col = (wv + n * 4) * 16 + cl;
      float bb = eb1[col];
#pragma unroll
      for (int r = 0; r < 4; ++r) sT[(quad * 4 + r) * 132 + col] = acc[n][r] + bb;
    }
  }
  __syncthreads();
  ln16(sT, SX, eg1, eB1, mreg, i0, tid, 0);
  __syncthreads();
  // E2 (K=128)
  {
    bf16x8 a2[4];
#pragma unroll
    for (int kc = 0; kc < 4; ++kc) a2[kc] = ((const bf16x8*)SX)[kc * 64 + lane];
    floatx4 acc[2];
    acc[0] = 0; acc[1] = 0;
#pragma unroll
    for (int kc = 0; kc < 4; ++kc)
#pragma unroll
      for (int n = 0; n < 2; ++n) {
        bf16x8 bw = ((const bf16x8*)w2pk)[((wv + n * 4) * 4 + kc) * 64 + lane];
        acc[n] = __builtin_amdgcn_mfma_f32_16x16x32_bf16(a2[kc], bw, acc[n], 0, 0, 0);
      }
    __syncthreads();  // order sT reads in ln16 above vs sT writes below
#pragma unroll
    for (int n = 0; n < 2; ++n) {
      int col = (wv + n * 4) * 16 + cl;
      float bb = eb2[col];
#pragma unroll
      for (int r = 0; r < 4; ++r) sT[(quad * 4 + r) * 132 + col] = acc[n][r] + bb;
    }
  }
  __syncthreads();
  ln16(sT, SX, eg2, eB2, mreg, i0, tid, 1);
  __syncthreads();
  qkv_tail(SX, sTv, b, i0, wcat0, bcat0, hqg, hkT, vpk, tid);
}

// ---------------------------------------------------------------------------
// layer: 512 blocks = (b, 16-row quarter) x 256 thr. LDS ~18.7 KB.
// Score phase reads hq + We2 as wave-uniform scalar loads (no staging barrier).
template <bool LAST>
__global__ __launch_bounds__(256, 4) void layer_kernel(
    const unsigned int* __restrict__ hq_in, const unsigned int* __restrict__ hkT_in,
    const __bf16* __restrict__ vp_in, const float* __restrict__ mask,
    const unsigned int* __restrict__ w2hl, const float* __restrict__ be2p,
    const __bf16* __restrict__ wopk_l, const float* __restrict__ bo_l,
    const float* __restrict__ og_l, const float* __restrict__ oB_l,
    const __bf16* __restrict__ wcat_n, const float* __restrict__ bcat_n,
    unsigned int* __restrict__ hq_out, unsigned int* __restrict__ hkT_out,
    __bf16* __restrict__ vpk_out, float* __restrict__ poolp) {
  __shared__ __align__(16) __bf16 pA[1024];   // 2 KB packed-A attn
  __shared__ __align__(16) __bf16 pA2[2048];  // 4 KB packed-A agg
  __shared__ __align__(16) __bf16 SX[2048];   // 4 KB packed-A x
  __shared__ __align__(16) float sTv[16 * 132];
  float* sT = sTv;
  int tid = threadIdx.x, blk = blockIdx.x;
  int lane = tid & 63, wv = tid >> 6, quad = lane >> 4, cl = lane & 15;
  int b = blk >> 2, i0 = (blk & 3) * 16;
  float mreg = mask[b * 64 + lane];

  // scores + softmax -> pA. hq rows + We2 are lane-invariant -> scalar loads.
  {
    int j = lane;
    const unsigned int* hkg = hkT_in + b * 4096;
    int wvu = __builtin_amdgcn_readfirstlane(wv);
    const unsigned int* hqr = hq_in + (b * 64 + i0 + wvu * 4) * 64;  // uniform
    float accs[4] = {0.f, 0.f, 0.f, 0.f};
    h2 hz = {(_Float16)0.0f, (_Float16)0.0f};
#pragma unroll 4
    for (int c4 = 0; c4 < 16; ++c4) {
      int hp0 = c4 * 4;
      uint4 w2v = *(const uint4*)(w2hl + hp0);   // uniform (s_load)
      uint4 hkv;
      hkv.x = hkg[(hp0 + 0) * 64 + j];
      hkv.y = hkg[(hp0 + 1) * 64 + j];
      hkv.z = hkg[(hp0 + 2) * 64 + j];
      hkv.w = hkg[(hp0 + 3) * 64 + j];
#pragma unroll
      for (int il = 0; il < 4; ++il) {
        uint4 hqv = *(const uint4*)(hqr + il * 64 + hp0);  // uniform (s_load)
        U32H2 ha, hb, wc2;
        h2 s2;
        ha.u = hqv.x; hb.u = hkv.x; wc2.u = w2v.x;
        s2 = __builtin_elementwise_max(ha.h + hb.h, hz);
        accs[il] = fdot2h(s2, wc2.h, accs[il]);
        ha.u = hqv.y; hb.u = hkv.y; wc2.u = w2v.y;
        s2 = __builtin_elementwise_max(ha.h + hb.h, hz);
        accs[il] = fdot2h(s2, wc2.h, accs[il]);
        ha.u = hqv.z; hb.u = hkv.z; wc2.u = w2v.z;
        s2 = __builtin_elementwise_max(ha.h + hb.h, hz);
        accs[il] = fdot2h(s2, wc2.h, accs[il]);
        ha.u = hqv.w; hb.u = hkv.w; wc2.u = w2v.w;
        s2 = __builtin_elementwise_max(ha.h + hb.h, hz);
        accs[il] = fdot2h(s2, wc2.h, accs[il]);
      }
    }
    float be2v = be2p[0];
    float mj = mreg;
#pragma unroll
    for (int kk = 0; kk < 4; ++kk) {
      int il = wv * 4 + kk;
      float mi = __shfl(mreg, i0 + il);
      float m2 = mi * mj;
      float sc = (m2 > 0.f) ? accs[kk] + be2v : NEGI;
      float mx = sc;
#pragma unroll
      for (int off = 32; off >= 1; off >>= 1) mx = fmaxf(mx, __shfl_xor(mx, off));
      float p = __expf(sc - mx);
      float sm = p;
#pragma unroll
      for (int off = 32; off >= 1; off >>= 1) sm += __shfl_xor(sm, off);
      float a = p / sm * m2;
      pA[((j >> 5) * 64 + ((j >> 3) & 3) * 16 + il) * 8 + (j & 7)] = (__bf16)a;
    }
  }
  __syncthreads();

  // agg = attn @ v (B from global vpk) -> pA2 packed-A
  {
    bf16x8 aat[2];
#pragma unroll
    for (int kc = 0; kc < 2; ++kc) aat[kc] = ((const bf16x8*)pA)[kc * 64 + lane];
    floatx4 acc[2];
    acc[0] = 0; acc[1] = 0;
#pragma unroll
    for (int kc = 0; kc < 2; ++kc)
#pragma unroll
      for (int n = 0; n < 2; ++n) {
        bf16x8 bw = ((const bf16x8*)vp_in)[b * 1024 + ((wv + n * 4) * 2 + kc) * 64 + lane];
        acc[n] = __builtin_amdgcn_mfma_f32_16x16x32_bf16(aat[kc], bw, acc[n], 0, 0, 0);
      }
#pragma unroll
    for (int n = 0; n < 2; ++n) {
      int hcol = (wv + n * 4) * 16 + cl;
#pragma unroll
      for (int r = 0; r < 4; ++r) {
        int i = quad * 4 + r;
        pA2[((hcol >> 5) * 64 + ((hcol >> 3) & 3) * 16 + i) * 8 + (hcol & 7)] =
            (__bf16)acc[n][r];
      }
    }
  }
  __syncthreads();

  // Wo GEMM
  {
    bf16x8 ag[4];
#pragma unroll
    for (int kc = 0; kc < 4; ++kc) ag[kc] = ((const bf16x8*)pA2)[kc * 64 + lane];
    floatx4 acc[2];
    acc[0] = 0; acc[1] = 0;
#pragma unroll
    for (int kc = 0; kc < 4; ++kc)
#pragma unroll
      for (int n = 0; n < 2; ++n) {
        bf16x8 bw = ((const bf16x8*)wopk_l)[((wv + n * 4) * 4 + kc) * 64 + lane];
        acc[n] = __builtin_amdgcn_mfma_f32_16x16x32_bf16(ag[kc], bw, acc[n], 0, 0, 0);
      }
#pragma unroll
    for (int n = 0; n < 2; ++n) {
      int col = (wv + n * 4) * 16 + cl;
      float bb = bo_l[col];
#pragma unroll
      for (int r = 0; r < 4; ++r) sT[(quad * 4 + r) * 132 + col] = acc[n][r] + bb;
    }
  }
  __syncthreads();
  ln16(sT, SX, og_l, oB_l, mreg, i0, tid, LAST ? 2 : 1);
  __syncthreads();
  if (!LAST) {
    qkv_tail(SX, sTv, b, i0, wcat_n, bcat_n, hq_out, hkT_out, vpk_out, tid);
  } else {
    if (tid < 128) {
      float s = 0.f;
#pragma unroll
      for (int r = 0; r < 16; ++r) s += sT[r * 132 + tid];
      poolp[blk * 128 + tid] = s;
    }
  }
}

// ---------------------------------------------------------------------------
// decoder: 128 blocks x 256 thr, 2-way split-K (r7-verified body, standalone).
__global__ __launch_bounds__(256) void dec_kernel(
    const float* __restrict__ bfeat, const float* __restrict__ poolp,
    const float* __restrict__ mask,
    const float* __restrict__ dW1, const float* __restrict__ db1,
    const float* __restrict__ dg1, const float* __restrict__ dB1,
    const float* __restrict__ dW2, const float* __restrict__ db2,
    const float* __restrict__ dg2, const float* __restrict__ dB2,
    const float* __restrict__ dW3, const float* __restrict__ db3,
    float* __restrict__ out) {
  __shared__ float sd[144];
  __shared__ float part[256];
  __shared__ float szz[128];
  __shared__ float red[4];
  int b = blockIdx.x, tid = threadIdx.x;
  int lane = tid & 63;
  float mreg = mask[b * 64 + lane];
  float den = mreg;
#pragma unroll
  for (int off = 32; off >= 1; off >>= 1) den += __shfl_xor(den, off);
  den = fmaxf(den, 1.f);
  if (tid < 7) sd[tid] = bfeat[b * 7 + tid];
  if (tid < 128) {
    float pooled = poolp[(b * 4 + 0) * 128 + tid] + poolp[(b * 4 + 1) * 128 + tid] +
                   poolp[(b * 4 + 2) * 128 + tid] + poolp[(b * 4 + 3) * 128 + tid];
    sd[7 + tid] = pooled / den;
  }
  __syncthreads();
  int t = tid & 127, g2 = tid >> 7;
  {
    float zp = 0.f;
    for (int k = g2; k < 135; k += 2) zp = fmaf(sd[k], dW1[k * 128 + t], zp);
    part[g2 * 128 + t] = zp;
  }
  __syncthreads();
  {
    float z = db1[t] + part[t] + part[128 + t];
    float s = z, q = z * z;
#pragma unroll
    for (int off = 32; off >= 1; off >>= 1) { s += __shfl_xor(s, off); q += __shfl_xor(q, off); }
    if (tid < 128 && lane == 0) { red[(tid >> 6) * 2] = s; red[(tid >> 6) * 2 + 1] = q; }
    __syncthreads();
    float S = red[0] + red[2], Q = red[1] + red[3];
    float m = S * (1.f / 128.f);
    float rs = rsqrtf(fmaxf(Q * (1.f / 128.f) - m * m, 0.f) + EPS);
    z = fmaxf((z - m) * rs * dg1[t] + dB1[t], 0.f);
    __syncthreads();
    if (tid < 128) szz[t] = z;
  }
  __syncthreads();
  {
    float zp = 0.f;
    for (int k = g2; k < 128; k += 2) zp = fmaf(szz[k], dW2[k * 128 + t], zp);
    part[g2 * 128 + t] = zp;
  }
  __syncthreads();
  {
    float y = db2[t] + part[t] + part[128 + t];
    float s = y, q = y * y;
#pragma unroll
    for (int off = 32; off >= 1; off >>= 1) { s += __shfl_xor(s, off); q += __shfl_xor(q, off); }
    if (tid < 128 && lane == 0) { red[(tid >> 6) * 2] = s; red[(tid >> 6) * 2 + 1] = q; }
    __syncthreads();
    float S = red[0] + red[2], Q = red[1] + red[3];
    float m = S * (1.f / 128.f);
    float rs = rsqrtf(fmaxf(Q * (1.f / 128.f) - m * m, 0.f) + EPS);
    y = fmaxf((y - m) * rs * dg2[t] + dB2[t], 0.f);
    __syncthreads();
    if (tid < 128) szz[t] = y;
  }
  __syncthreads();
  if (tid < 7) {
    float o = db3[tid];
    for (int k = 0; k < 128; ++k) o = fmaf(szz[k], dW3[k * 7 + tid], o);
    out[b * 7 + tid] = o;
  }
}

// ---------------------------------------------------------------------------
extern "C" void kernel_launch(void* const* d_in, const int* in_sizes, int n_in,
                              void* d_out, int out_size, void* d_ws, size_t ws_size,
                              hipStream_t stream) {
  const float* bf   = (const float*)d_in[0];
  const float* emb  = (const float*)d_in[1];
  const float* mask = (const float*)d_in[2];
  const float* eW1 = (const float*)d_in[3];
  const float* eb1 = (const float*)d_in[4];
  const float* eg1 = (const float*)d_in[5];
  const float* eB1 = (const float*)d_in[6];
  const float* eW2 = (const float*)d_in[7];
  const float* eb2 = (const float*)d_in[8];
  const float* eg2 = (const float*)d_in[9];
  const float* eB2 = (const float*)d_in[10];
  const float* Wq = (const float*)d_in[11];
  const float* bq = (const float*)d_in[12];
  const float* Wk = (const float*)d_in[13];
  const float* bk = (const float*)d_in[14];
  const float* Wv = (const float*)d_in[15];
  const float* bv = (const float*)d_in[16];
  const float* We1 = (const float*)d_in[17];
  const float* be1 = (const float*)d_in[18];
  const float* We2 = (const float*)d_in[19];
  const float* be2 = (const float*)d_in[20];
  const float* Wo = (const float*)d_in[21];
  const float* bo = (const float*)d_in[22];
  const float* og = (const float*)d_in[23];
  const float* oB = (const float*)d_in[24];
  const float* dW1 = (const float*)d_in[25];
  const float* db1 = (const float*)d_in[26];
  const float* dg1 = (const float*)d_in[27];
  const float* dB1 = (const float*)d_in[28];
  const float* dW2 = (const float*)d_in[29];
  const float* db2 = (const float*)d_in[30];
  const float* dg2 = (const float*)d_in[31];
  const float* dB2 = (const float*)d_in[32];
  const float* dW3 = (const float*)d_in[33];
  const float* db3 = (const float*)d_in[34];
  float* out = (float*)d_out;

  char* ws = (char*)d_ws;
  float* bcat = (float*)(ws + 1024);                 // 4608 B
  unsigned int* w2hg = (unsigned int*)(ws + 6144);   // 768 B
  __bf16* w1pk   = (__bf16*)(ws + 8192);             // 16 KB
  __bf16* w2pk   = (__bf16*)(ws + 24576);            // 32 KB
  __bf16* wcatpk = (__bf16*)(ws + 57344);            // 288 KB
  __bf16* wopk   = (__bf16*)(ws + 352256);           // 96 KB
  unsigned int* hqg = (unsigned int*)(ws + 524288);  // 2 x 2 MB
  unsigned int* hkT = (unsigned int*)(ws + 4718592); // 2 x 2 MB
  __bf16* vpk = (__bf16*)(ws + 8912896);             // 2 x 2 MB
  float* poolp = (float*)(ws + 13107200);            // 256 KB

  prep_kernel<<<57, 256, 0, stream>>>(Wq, bq, Wk, bk, bv, We1, be1,
                                      eW1, eW2, Wv, Wo, We2,
                                      w1pk, w2pk, wcatpk, wopk, bcat, w2hg);
  enc_qkv_kernel<<<512, 256, 0, stream>>>(emb, mask, eb1, eg1, eB1, eb2, eg2, eB2,
                                          w1pk, w2pk, wcatpk, bcat, hqg, hkT, vpk);
  layer_kernel<false><<<512, 256, 0, stream>>>(
      hqg, hkT, vpk, mask, w2hg, be2, wopk, bo, og, oB,
      wcatpk + 49152, bcat + 384,
      hqg + 524288, hkT + 524288, vpk + 1048576, nullptr);
  layer_kernel<false><<<512, 256, 0, stream>>>(
      hqg + 524288, hkT + 524288, vpk + 1048576, mask, w2hg + 64, be2 + 1,
      wopk + 16384, bo + 128, og + 128, oB + 128,
      wcatpk + 2 * 49152, bcat + 2 * 384,
      hqg, hkT, vpk, nullptr);
  layer_kernel<true><<<512, 256, 0, stream>>>(
      hqg, hkT, vpk, mask, w2hg + 128, be2 + 2,
      wopk + 2 * 16384, bo + 256, og + 256, oB + 256,
      nullptr, nullptr, nullptr, nullptr, nullptr, poolp);
  dec_kernel<<<128, 256, 0, stream>>>(bf, poolp, mask, dW1, db1, dg1, dB1,
                                      dW2, db2, dg2, dB2, dW3, db3, out);
}

// Round 11
// 195.265 us; speedup vs baseline: 1.1370x; 1.1370x over previous
//
#include <hip/hip_runtime.h>

// MaskedGNN MI355X — round 11: r10 with dec_kernel rebuilt for structural
// memory-level parallelism (8-way K-split x float4 column loads; r10's
// scalar split-K compiled to a 12-VGPR non-pipelined loop = 48 us).
// 6 launches: prep -> enc+qkv0 -> layer x3 -> dec.
// H=128, N=64, B=128, L=3, F=7, E=64.
// MFMA 16x16x32 bf16 fragments:
//   A-frag: lane holds A[m=lane&15][k=(lane>>4)*8+j]
//   B-frag: lane holds B[k=(lane>>4)*8+j][n=lane&15]
//   C/D:    col=lane&15, row=(lane>>4)*4+reg

constexpr float EPS = 1e-5f;
constexpr float NEGI = -1e9f;

typedef __bf16 bf16x8 __attribute__((ext_vector_type(8)));
typedef float floatx4 __attribute__((ext_vector_type(4)));
typedef _Float16 h2 __attribute__((ext_vector_type(2)));
union U32H2 { unsigned int u; h2 h; };

__device__ __forceinline__ unsigned int pkh2(float a, float b) {
  U32H2 u; u.h[0] = (_Float16)a; u.h[1] = (_Float16)b; return u.u;
}
__device__ __forceinline__ float fdot2h(h2 a, h2 b, float c) {
#if __has_builtin(__builtin_amdgcn_fdot2)
  return __builtin_amdgcn_fdot2(a, b, c, false);
#else
  return c + (float)a[0] * (float)b[0] + (float)a[1] * (float)b[1];
#endif
}
__device__ __forceinline__ bf16x8 cvt8(const float* p) {
  float t[8];
  *(float4*)t = *(const float4*)p;
  *(float4*)(t + 4) = *(const float4*)(p + 4);
  bf16x8 r;
#pragma unroll
  for (int j = 0; j < 8; ++j) r[j] = (__bf16)t[j];
  return r;
}

// ---------------------------------------------------------------------------
// prep (verified r3/r6): fold Wqe/Wke, pack weights to MFMA-B, bcat, + w2hg.
__global__ __launch_bounds__(256) void prep_kernel(
    const float* __restrict__ Wq, const float* __restrict__ bq,
    const float* __restrict__ Wk, const float* __restrict__ bk,
    const float* __restrict__ bv, const float* __restrict__ We1,
    const float* __restrict__ be1,
    const float* __restrict__ eW1, const float* __restrict__ eW2,
    const float* __restrict__ Wv, const float* __restrict__ Wo,
    const float* __restrict__ We2,
    __bf16* __restrict__ w1pk, __bf16* __restrict__ w2pk,
    __bf16* __restrict__ wcatpk, __bf16* __restrict__ wopk,
    float* __restrict__ bcat, unsigned int* __restrict__ w2hg) {
  int tid = threadIdx.x, blk = blockIdx.x;
  if (blk < 48) {
    __shared__ float sB[128 * 16];
    __shared__ float sF[128 * 17];
    int jb = blk >> 3, cc = blk & 7;
    int l = jb >> 1, w = jb & 1;
    const float* A = (w ? Wk : Wq) + l * 16384;
    const float* Bm = We1 + l * 32768 + w * 16384;
    int c0 = cc * 16;
    for (int idx = tid; idx < 2048; idx += 256) {
      int m = idx >> 4, c = idx & 15;
      sB[idx] = Bm[m * 128 + c0 + c];
    }
    __syncthreads();
    int r = tid >> 1, c8 = (tid & 1) * 8;
    float acc[8] = {};
    const float4* A4 = (const float4*)(A + r * 128);
#pragma unroll 8
    for (int k4 = 0; k4 < 32; ++k4) {
      float4 a = A4[k4];
      float av[4] = {a.x, a.y, a.z, a.w};
#pragma unroll
      for (int kk = 0; kk < 4; ++kk)
#pragma unroll
        for (int c = 0; c < 8; ++c)
          acc[c] = fmaf(av[kk], sB[(k4 * 4 + kk) * 16 + c8 + c], acc[c]);
    }
    for (int c = 0; c < 8; ++c) sF[r * 17 + c8 + c] = acc[c];
    __syncthreads();
    int kc = tid >> 6, ln = tid & 63;
    int k0 = kc * 32 + (ln >> 4) * 8, n = ln & 15;
    bf16x8 pk;
#pragma unroll
    for (int j = 0; j < 8; ++j) pk[j] = (__bf16)sF[(k0 + j) * 17 + n];
    int ntg = 8 + w * 8 + cc;
    *((bf16x8*)(wcatpk + l * 49152) + (ntg * 4 + kc) * 64 + ln) = pk;
  } else if (blk < 56) {
    int job = blk - 48;
    const float* src;
    __bf16* dst;
    int KCH = 4;
    if (job == 0) { src = eW1; dst = w1pk; KCH = 2; }
    else if (job == 1) { src = eW2; dst = w2pk; }
    else if (job < 5) { int l = job - 2; src = Wv + l * 16384; dst = wcatpk + l * 49152; }
    else { int l = job - 5; src = Wo + l * 16384; dst = wopk + l * 16384; }
    for (int s = tid; s < 8 * KCH * 64; s += 256) {
      int ln = s & 63, q = s >> 6;
      int kc = q % KCH, nt = q / KCH;
      int k0 = kc * 32 + (ln >> 4) * 8, n = nt * 16 + (ln & 15);
      bf16x8 pk;
#pragma unroll
      for (int j = 0; j < 8; ++j) pk[j] = (__bf16)src[(k0 + j) * 128 + n];
      *((bf16x8*)dst + (nt * KCH + kc) * 64 + ln) = pk;
    }
  } else {
    for (int idx = tid; idx < 3 * 384; idx += 256) {
      int l = idx / 384, c = idx % 384;
      float val;
      if (c < 128) {
        val = bv[l * 128 + c];
      } else if (c < 256) {
        int cc2 = c - 128;
        float s = 0.f;
        for (int k = 0; k < 128; ++k) s += bq[l * 128 + k] * We1[l * 32768 + k * 128 + cc2];
        val = s;
      } else {
        int cc2 = c - 256;
        float s = be1[l * 128 + cc2];
        for (int k = 0; k < 128; ++k) s += bk[l * 128 + k] * We1[l * 32768 + 16384 + k * 128 + cc2];
        val = s;
      }
      bcat[l * 384 + c] = val;
    }
    for (int idx = tid; idx < 192; idx += 256) {
      int l = idx >> 6, c = idx & 63;
      w2hg[l * 64 + c] = pkh2(We2[l * 128 + 2 * c], We2[l * 128 + 2 * c + 1]);
    }
  }
}

// ---------------------------------------------------------------------------
// LN over sT (16 rows x 128, stride 132). mode 0: pack->SX. mode 1: mask+pack.
// mode 2: mask + write back to sT (for pooling).
__device__ __forceinline__ void ln16(float* sT, __bf16* SX, const float* __restrict__ g,
                                     const float* __restrict__ be, float mreg,
                                     int i0, int tid, int mode) {
  int r = tid >> 4, c0 = tid & 15;
  const float* base = sT + r * 132;
  float s = 0.f, q = 0.f;
#pragma unroll
  for (int k = 0; k < 8; ++k) { float v = base[c0 + k * 16]; s += v; q += v * v; }
  s += __shfl_xor(s, 1); s += __shfl_xor(s, 2); s += __shfl_xor(s, 4); s += __shfl_xor(s, 8);
  q += __shfl_xor(q, 1); q += __shfl_xor(q, 2); q += __shfl_xor(q, 4); q += __shfl_xor(q, 8);
  float m = s * (1.f / 128.f);
  float rs = rsqrtf(fmaxf(q * (1.f / 128.f) - m * m, 0.f) + EPS);
  float mk = (mode >= 1) ? __shfl(mreg, i0 + r) : 1.f;
  int c8 = c0 * 8;
  float vals[8];
  *(float4*)vals = *(const float4*)(base + c8);
  *(float4*)(vals + 4) = *(const float4*)(base + c8 + 4);
#pragma unroll
  for (int k = 0; k < 8; ++k)
    vals[k] = fmaxf((vals[k] - m) * rs * g[c8 + k] + be[c8 + k], 0.f) * mk;
  if (mode < 2) {
    bf16x8 pk;
#pragma unroll
    for (int k = 0; k < 8; ++k) pk[k] = (__bf16)vals[k];
    ((bf16x8*)SX)[(c8 >> 5) * 64 + ((c8 >> 3) & 3) * 16 + r] = pk;
  } else {
    *(float4*)(sT + r * 132 + c8) = *(float4*)vals;
    *(float4*)(sT + r * 132 + c8 + 4) = *(float4*)(vals + 4);
  }
}

// qkv tail (verified r9): x(SX packed-A) @ wcat -> v (packed-B via sTv LDS),
// hq/hk via transposed MFMA -> direct global writes.
__device__ __forceinline__ void qkv_tail(
    const __bf16* SX, float* sTv,
    int b, int i0, const __bf16* __restrict__ wc, const float* __restrict__ bc,
    unsigned int* __restrict__ hqg_o, unsigned int* __restrict__ hkT_o,
    __bf16* __restrict__ vpk_o, int tid) {
  int lane = tid & 63, wv = tid >> 6, quad = lane >> 4, cl = lane & 15;
  bf16x8 ax[4];
#pragma unroll
  for (int kc = 0; kc < 4; ++kc) ax[kc] = ((const bf16x8*)SX)[kc * 64 + lane];
  floatx4 acc[6];
#pragma unroll
  for (int n = 0; n < 6; ++n) acc[n] = 0;
#pragma unroll
  for (int kc = 0; kc < 4; ++kc)
#pragma unroll
    for (int n = 0; n < 6; ++n) {
      bf16x8 bw = ((const bf16x8*)wc)[((wv + n * 4) * 4 + kc) * 64 + lane];
      if (n < 2)
        acc[n] = __builtin_amdgcn_mfma_f32_16x16x32_bf16(ax[kc], bw, acc[n], 0, 0, 0);
      else
        acc[n] = __builtin_amdgcn_mfma_f32_16x16x32_bf16(bw, ax[kc], acc[n], 0, 0, 0);
    }
#pragma unroll
  for (int n = 0; n < 6; ++n) {
    int g = wv + n * 4;
    if (n < 2) {                       // v: C-layout -> sTv
      int coll = g * 16 + cl;
      float bb = bc[coll];
#pragma unroll
      for (int r = 0; r < 4; ++r) sTv[(quad * 4 + r) * 132 + coll] = acc[n][r] + bb;
    } else if (n < 4) {                // hq^T: lane holds h=hb..hb+3 of row i=cl
      int hb = (g - 8) * 16 + quad * 4;
      float4 bb4 = *(const float4*)(bc + 128 + hb);
      uint2 o;
      o.x = pkh2(acc[n][0] + bb4.x, acc[n][1] + bb4.y);
      o.y = pkh2(acc[n][2] + bb4.z, acc[n][3] + bb4.w);
      *(uint2*)(hqg_o + (b * 64 + i0 + cl) * 64 + (hb >> 1)) = o;
    } else {                           // hk^T: lane holds h=hb..hb+3 of row j=cl
      int hb = (g - 16) * 16 + quad * 4;
      float4 bb4 = *(const float4*)(bc + 256 + hb);
      hkT_o[b * 4096 + (hb >> 1) * 64 + i0 + cl] =
          pkh2(acc[n][0] + bb4.x, acc[n][1] + bb4.y);
      hkT_o[b * 4096 + ((hb >> 1) + 1) * 64 + i0 + cl] =
          pkh2(acc[n][2] + bb4.z, acc[n][3] + bb4.w);
    }
  }
  __syncthreads();
  {  // v -> packed-B bf16 (r3/r6-verified mapping)
    int nt = tid >> 5, dq = (tid >> 4) & 1, c2 = tid & 15;
    int kcv = i0 >> 5, qg = ((i0 & 31) >> 3) + dq;
    bf16x8 pk;
#pragma unroll
    for (int jj = 0; jj < 8; ++jj) pk[jj] = (__bf16)sTv[(dq * 8 + jj) * 132 + nt * 16 + c2];
    ((bf16x8*)vpk_o)[b * 1024 + (nt * 2 + kcv) * 64 + qg * 16 + c2] = pk;
  }
}

// ---------------------------------------------------------------------------
// encoder + qkv0 (verified r9): 512 blocks = (b, 16-row quarter) x 256 thr.
__global__ __launch_bounds__(256) void enc_qkv_kernel(
    const float* __restrict__ emb, const float* __restrict__ mask,
    const float* __restrict__ eb1, const float* __restrict__ eg1, const float* __restrict__ eB1,
    const float* __restrict__ eb2, const float* __restrict__ eg2, const float* __restrict__ eB2,
    const __bf16* __restrict__ w1pk, const __bf16* __restrict__ w2pk,
    const __bf16* __restrict__ wcat0, const float* __restrict__ bcat0,
    unsigned int* __restrict__ hqg, unsigned int* __restrict__ hkT,
    __bf16* __restrict__ vpk) {
  __shared__ __align__(16) __bf16 SX[2048];
  __shared__ __align__(16) float sTv[16 * 132];
  float* sT = sTv;
  int tid = threadIdx.x, blk = blockIdx.x;
  int lane = tid & 63, wv = tid >> 6, quad = lane >> 4, cl = lane & 15;
  int b = blk >> 2, i0 = (blk & 3) * 16;
  float mreg = mask[b * 64 + lane];

  // E1 (K=64)
  {
    bf16x8 a1[2];
#pragma unroll
    for (int kc = 0; kc < 2; ++kc)
      a1[kc] = cvt8(emb + (b * 64 + i0 + cl) * 64 + kc * 32 + quad * 8);
    floatx4 acc[2];
    acc[0] = 0; acc[1] = 0;
#pragma unroll
    for (int kc = 0; kc < 2; ++kc)
#pragma unroll
      for (int n = 0; n < 2; ++n) {
        bf16x8 bw = ((const bf16x8*)w1pk)[((wv + n * 4) * 2 + kc) * 64 + lane];
        acc[n] = __builtin_amdgcn_mfma_f32_16x16x32_bf16(a1[kc], bw, acc[n], 0, 0, 0);
      }
#pragma unroll
    for (int n = 0; n < 2; ++n) {
      int col = (wv + n * 4) * 16 + cl;
      float bb = eb1[col];
#pragma unroll
      for (int r = 0; r < 4; ++r) sT[(quad * 4 + r) * 132 + col] = acc[n][r] + bb;
    }
  }
  __syncthreads();
  ln16(sT, SX, eg1, eB1, mreg, i0, tid, 0);
  __syncthreads();
  // E2 (K=128)
  {
    bf16x8 a2[4];
#pragma unroll
    for (int kc = 0; kc < 4; ++kc) a2[kc] = ((const bf16x8*)SX)[kc * 64 + lane];
    floatx4 acc[2];
    acc[0] = 0; acc[1] = 0;
#pragma unroll
    for (int kc = 0; kc < 4; ++kc)
#pragma unroll
      for (int n = 0; n < 2; ++n) {
        bf16x8 bw = ((const bf16x8*)w2pk)[((wv + n * 4) * 4 + kc) * 64 + lane];
        acc[n] = __builtin_amdgcn_mfma_f32_16x16x32_bf16(a2[kc], bw, acc[n], 0, 0, 0);
      }
    __syncthreads();  // order sT reads in ln16 above vs sT writes below
#pragma unroll
    for (int n = 0; n < 2; ++n) {
      int col = (wv + n * 4) * 16 + cl;
      float bb = eb2[col];
#pragma unroll
      for (int r = 0; r < 4; ++r) sT[(quad * 4 + r) * 132 + col] = acc[n][r] + bb;
    }
  }
  __syncthreads();
  ln16(sT, SX, eg2, eB2, mreg, i0, tid, 1);
  __syncthreads();
  qkv_tail(SX, sTv, b, i0, wcat0, bcat0, hqg, hkT, vpk, tid);
}

// ---------------------------------------------------------------------------
// layer (verified r10): 512 blocks = (b, 16-row quarter) x 256 thr.
// Score phase reads hq + We2 as wave-uniform scalar loads (no staging barrier).
template <bool LAST>
__global__ __launch_bounds__(256, 4) void layer_kernel(
    const unsigned int* __restrict__ hq_in, const unsigned int* __restrict__ hkT_in,
    const __bf16* __restrict__ vp_in, const float* __restrict__ mask,
    const unsigned int* __restrict__ w2hl, const float* __restrict__ be2p,
    const __bf16* __restrict__ wopk_l, const float* __restrict__ bo_l,
    const float* __restrict__ og_l, const float* __restrict__ oB_l,
    const __bf16* __restrict__ wcat_n, const float* __restrict__ bcat_n,
    unsigned int* __restrict__ hq_out, unsigned int* __restrict__ hkT_out,
    __bf16* __restrict__ vpk_out, float* __restrict__ poolp) {
  __shared__ __align__(16) __bf16 pA[1024];   // 2 KB packed-A attn
  __shared__ __align__(16) __bf16 pA2[2048];  // 4 KB packed-A agg
  __shared__ __align__(16) __bf16 SX[2048];   // 4 KB packed-A x
  __shared__ __align__(16) float sTv[16 * 132];
  float* sT = sTv;
  int tid = threadIdx.x, blk = blockIdx.x;
  int lane = tid & 63, wv = tid >> 6, quad = lane >> 4, cl = lane & 15;
  int b = blk >> 2, i0 = (blk & 3) * 16;
  float mreg = mask[b * 64 + lane];

  // scores + softmax -> pA. hq rows + We2 are lane-invariant -> scalar loads.
  {
    int j = lane;
    const unsigned int* hkg = hkT_in + b * 4096;
    int wvu = __builtin_amdgcn_readfirstlane(wv);
    const unsigned int* hqr = hq_in + (b * 64 + i0 + wvu * 4) * 64;  // uniform
    float accs[4] = {0.f, 0.f, 0.f, 0.f};
    h2 hz = {(_Float16)0.0f, (_Float16)0.0f};
#pragma unroll 4
    for (int c4 = 0; c4 < 16; ++c4) {
      int hp0 = c4 * 4;
      uint4 w2v = *(const uint4*)(w2hl + hp0);   // uniform (s_load)
      uint4 hkv;
      hkv.x = hkg[(hp0 + 0) * 64 + j];
      hkv.y = hkg[(hp0 + 1) * 64 + j];
      hkv.z = hkg[(hp0 + 2) * 64 + j];
      hkv.w = hkg[(hp0 + 3) * 64 + j];
#pragma unroll
      for (int il = 0; il < 4; ++il) {
        uint4 hqv = *(const uint4*)(hqr + il * 64 + hp0);  // uniform (s_load)
        U32H2 ha, hb, wc2;
        h2 s2;
        ha.u = hqv.x; hb.u = hkv.x; wc2.u = w2v.x;
        s2 = __builtin_elementwise_max(ha.h + hb.h, hz);
        accs[il] = fdot2h(s2, wc2.h, accs[il]);
        ha.u = hqv.y; hb.u = hkv.y; wc2.u = w2v.y;
        s2 = __builtin_elementwise_max(ha.h + hb.h, hz);
        accs[il] = fdot2h(s2, wc2.h, accs[il]);
        ha.u = hqv.z; hb.u = hkv.z; wc2.u = w2v.z;
        s2 = __builtin_elementwise_max(ha.h + hb.h, hz);
        accs[il] = fdot2h(s2, wc2.h, accs[il]);
        ha.u = hqv.w; hb.u = hkv.w; wc2.u = w2v.w;
        s2 = __builtin_elementwise_max(ha.h + hb.h, hz);
        accs[il] = fdot2h(s2, wc2.h, accs[il]);
      }
    }
    float be2v = be2p[0];
    float mj = mreg;
#pragma unroll
    for (int kk = 0; kk < 4; ++kk) {
      int il = wv * 4 + kk;
      float mi = __shfl(mreg, i0 + il);
      float m2 = mi * mj;
      float sc = (m2 > 0.f) ? accs[kk] + be2v : NEGI;
      float mx = sc;
#pragma unroll
      for (int off = 32; off >= 1; off >>= 1) mx = fmaxf(mx, __shfl_xor(mx, off));
      float p = __expf(sc - mx);
      float sm = p;
#pragma unroll
      for (int off = 32; off >= 1; off >>= 1) sm += __shfl_xor(sm, off);
      float a = p / sm * m2;
      pA[((j >> 5) * 64 + ((j >> 3) & 3) * 16 + il) * 8 + (j & 7)] = (__bf16)a;
    }
  }
  __syncthreads();

  // agg = attn @ v (B from global vpk) -> pA2 packed-A
  {
    bf16x8 aat[2];
#pragma unroll
    for (int kc = 0; kc < 2; ++kc) aat[kc] = ((const bf16x8*)pA)[kc * 64 + lane];
    floatx4 acc[2];
    acc[0] = 0; acc[1] = 0;
#pragma unroll
    for (int kc = 0; kc < 2; ++kc)
#pragma unroll
      for (int n = 0; n < 2; ++n) {
        bf16x8 bw = ((const bf16x8*)vp_in)[b * 1024 + ((wv + n * 4) * 2 + kc) * 64 + lane];
        acc[n] = __builtin_amdgcn_mfma_f32_16x16x32_bf16(aat[kc], bw, acc[n], 0, 0, 0);
      }
#pragma unroll
    for (int n = 0; n < 2; ++n) {
      int hcol = (wv + n * 4) * 16 + cl;
#pragma unroll
      for (int r = 0; r < 4; ++r) {
        int i = quad * 4 + r;
        pA2[((hcol >> 5) * 64 + ((hcol >> 3) & 3) * 16 + i) * 8 + (hcol & 7)] =
            (__bf16)acc[n][r];
      }
    }
  }
  __syncthreads();

  // Wo GEMM
  {
    bf16x8 ag[4];
#pragma unroll
    for (int kc = 0; kc < 4; ++kc) ag[kc] = ((const bf16x8*)pA2)[kc * 64 + lane];
    floatx4 acc[2];
    acc[0] = 0; acc[1] = 0;
#pragma unroll
    for (int kc = 0; kc < 4; ++kc)
#pragma unroll
      for (int n = 0; n < 2; ++n) {
        bf16x8 bw = ((const bf16x8*)wopk_l)[((wv + n * 4) * 4 + kc) * 64 + lane];
        acc[n] = __builtin_amdgcn_mfma_f32_16x16x32_bf16(ag[kc], bw, acc[n], 0, 0, 0);
      }
#pragma unroll
    for (int n = 0; n < 2; ++n) {
      int col = (wv + n * 4) * 16 + cl;
      float bb = bo_l[col];
#pragma unroll
      for (int r = 0; r < 4; ++r) sT[(quad * 4 + r) * 132 + col] = acc[n][r] + bb;
    }
  }
  __syncthreads();
  ln16(sT, SX, og_l, oB_l, mreg, i0, tid, LAST ? 2 : 1);
  __syncthreads();
  if (!LAST) {
    qkv_tail(SX, sTv, b, i0, wcat_n, bcat_n, hq_out, hkT_out, vpk_out, tid);
  } else {
    if (tid < 128) {
      float s = 0.f;
#pragma unroll
      for (int r = 0; r < 16; ++r) s += sT[r * 132 + tid];
      poolp[blk * 128 + tid] = s;
    }
  }
}

// ---------------------------------------------------------------------------
// decoder: 128 blocks x 256 thr. 8-way K-split, float4 column loads -> deep
// MLP (r10's scalar split compiled to 12 VGPR / no pipelining -> 48 us).
__global__ __launch_bounds__(256) void dec_kernel(
    const float* __restrict__ bfeat, const float* __restrict__ poolp,
    const float* __restrict__ mask,
    const float* __restrict__ dW1, const float* __restrict__ db1,
    const float* __restrict__ dg1, const float* __restrict__ dB1,
    const float* __restrict__ dW2, const float* __restrict__ db2,
    const float* __restrict__ dg2, const float* __restrict__ dB2,
    const float* __restrict__ dW3, const float* __restrict__ db3,
    float* __restrict__ out) {
  __shared__ float sd[144];
  __shared__ float part[8 * 128];
  __shared__ float szz[128];
  __shared__ float red[4];
  int b = blockIdx.x, tid = threadIdx.x;
  int lane = tid & 63;
  float mreg = mask[b * 64 + lane];
  float den = mreg;
#pragma unroll
  for (int off = 32; off >= 1; off >>= 1) den += __shfl_xor(den, off);
  den = fmaxf(den, 1.f);
  if (tid < 7) sd[tid] = bfeat[b * 7 + tid];
  if (tid < 128) {
    float pooled = poolp[(b * 4 + 0) * 128 + tid] + poolp[(b * 4 + 1) * 128 + tid] +
                   poolp[(b * 4 + 2) * 128 + tid] + poolp[(b * 4 + 3) * 128 + tid];
    sd[7 + tid] = pooled / den;
  }
  __syncthreads();

  int t4 = (tid & 31) * 4, g8 = tid >> 5;
  {
    float4 zp = {0.f, 0.f, 0.f, 0.f};
#pragma unroll 4
    for (int k = g8; k < 135; k += 8) {
      float s = sd[k];
      float4 w = *(const float4*)(dW1 + k * 128 + t4);
      zp.x = fmaf(s, w.x, zp.x);
      zp.y = fmaf(s, w.y, zp.y);
      zp.z = fmaf(s, w.z, zp.z);
      zp.w = fmaf(s, w.w, zp.w);
    }
    *(float4*)(part + g8 * 128 + t4) = zp;
  }
  __syncthreads();
  int t = tid & 127;
  {
    float z = db1[t];
#pragma unroll
    for (int w = 0; w < 8; ++w) z += part[w * 128 + t];
    float s = z, q = z * z;
#pragma unroll
    for (int off = 32; off >= 1; off >>= 1) { s += __shfl_xor(s, off); q += __shfl_xor(q, off); }
    if (tid < 128 && lane == 0) { red[(tid >> 6) * 2] = s; red[(tid >> 6) * 2 + 1] = q; }
    __syncthreads();
    float S = red[0] + red[2], Q = red[1] + red[3];
    float m = S * (1.f / 128.f);
    float rs = rsqrtf(fmaxf(Q * (1.f / 128.f) - m * m, 0.f) + EPS);
    z = fmaxf((z - m) * rs * dg1[t] + dB1[t], 0.f);
    __syncthreads();
    if (tid < 128) szz[t] = z;
  }
  __syncthreads();
  {
    float4 zp = {0.f, 0.f, 0.f, 0.f};
#pragma unroll 4
    for (int k = g8; k < 128; k += 8) {
      float s = szz[k];
      float4 w = *(const float4*)(dW2 + k * 128 + t4);
      zp.x = fmaf(s, w.x, zp.x);
      zp.y = fmaf(s, w.y, zp.y);
      zp.z = fmaf(s, w.z, zp.z);
      zp.w = fmaf(s, w.w, zp.w);
    }
    *(float4*)(part + g8 * 128 + t4) = zp;
  }
  __syncthreads();
  {
    float y = db2[t];
#pragma unroll
    for (int w = 0; w < 8; ++w) y += part[w * 128 + t];
    float s = y, q = y * y;
#pragma unroll
    for (int off = 32; off >= 1; off >>= 1) { s += __shfl_xor(s, off); q += __shfl_xor(q, off); }
    if (tid < 128 && lane == 0) { red[(tid >> 6) * 2] = s; red[(tid >> 6) * 2 + 1] = q; }
    __syncthreads();
    float S = red[0] + red[2], Q = red[1] + red[3];
    float m = S * (1.f / 128.f);
    float rs = rsqrtf(fmaxf(Q * (1.f / 128.f) - m * m, 0.f) + EPS);
    y = fmaxf((y - m) * rs * dg2[t] + dB2[t], 0.f);
    __syncthreads();
    if (tid < 128) szz[t] = y;
  }
  __syncthreads();
  // out[7]: 112 threads = (t=idx%7, kg=idx/7 of 16), 8 k each -> part; reduce.
  if (tid < 112) {
    int t7 = tid % 7, kg = tid / 7;
    float o = 0.f;
#pragma unroll
    for (int k = 0; k < 8; ++k)
      o = fmaf(szz[kg * 8 + k], dW3[(kg * 8 + k) * 7 + t7], o);
    part[kg * 7 + t7] = o;
  }
  __syncthreads();
  if (tid < 7) {
    float o = db3[tid];
#pragma unroll
    for (int kg = 0; kg < 16; ++kg) o += part[kg * 7 + tid];
    out[b * 7 + tid] = o;
  }
}

// ---------------------------------------------------------------------------
extern "C" void kernel_launch(void* const* d_in, const int* in_sizes, int n_in,
                              void* d_out, int out_size, void* d_ws, size_t ws_size,
                              hipStream_t stream) {
  const float* bf   = (const float*)d_in[0];
  const float* emb  = (const float*)d_in[1];
  const float* mask = (const float*)d_in[2];
  const float* eW1 = (const float*)d_in[3];
  const float* eb1 = (const float*)d_in[4];
  const float* eg1 = (const float*)d_in[5];
  const float* eB1 = (const float*)d_in[6];
  const float* eW2 = (const float*)d_in[7];
  const float* eb2 = (const float*)d_in[8];
  const float* eg2 = (const float*)d_in[9];
  const float* eB2 = (const float*)d_in[10];
  const float* Wq = (const float*)d_in[11];
  const float* bq = (const float*)d_in[12];
  const float* Wk = (const float*)d_in[13];
  const float* bk = (const float*)d_in[14];
  const float* Wv = (const float*)d_in[15];
  const float* bv = (const float*)d_in[16];
  const float* We1 = (const float*)d_in[17];
  const float* be1 = (const float*)d_in[18];
  const float* We2 = (const float*)d_in[19];
  const float* be2 = (const float*)d_in[20];
  const float* Wo = (const float*)d_in[21];
  const float* bo = (const float*)d_in[22];
  const float* og = (const float*)d_in[23];
  const float* oB = (const float*)d_in[24];
  const float* dW1 = (const float*)d_in[25];
  const float* db1 = (const float*)d_in[26];
  const float* dg1 = (const float*)d_in[27];
  const float* dB1 = (const float*)d_in[28];
  const float* dW2 = (const float*)d_in[29];
  const float* db2 = (const float*)d_in[30];
  const float* dg2 = (const float*)d_in[31];
  const float* dB2 = (const float*)d_in[32];
  const float* dW3 = (const float*)d_in[33];
  const float* db3 = (const float*)d_in[34];
  float* out = (float*)d_out;

  char* ws = (char*)d_ws;
  float* bcat = (float*)(ws + 1024);                 // 4608 B
  unsigned int* w2hg = (unsigned int*)(ws + 6144);   // 768 B
  __bf16* w1pk   = (__bf16*)(ws + 8192);             // 16 KB
  __bf16* w2pk   = (__bf16*)(ws + 24576);            // 32 KB
  __bf16* wcatpk = (__bf16*)(ws + 57344);            // 288 KB
  __bf16* wopk   = (__bf16*)(ws + 352256);           // 96 KB
  unsigned int* hqg = (unsigned int*)(ws + 524288);  // 2 x 2 MB
  unsigned int* hkT = (unsigned int*)(ws + 4718592); // 2 x 2 MB
  __bf16* vpk = (__bf16*)(ws + 8912896);             // 2 x 2 MB
  float* poolp = (float*)(ws + 13107200);            // 256 KB

  prep_kernel<<<57, 256, 0, stream>>>(Wq, bq, Wk, bk, bv, We1, be1,
                                      eW1, eW2, Wv, Wo, We2,
                                      w1pk, w2pk, wcatpk, wopk, bcat, w2hg);
  enc_qkv_kernel<<<512, 256, 0, stream>>>(emb, mask, eb1, eg1, eB1, eb2, eg2, eB2,
                                          w1pk, w2pk, wcatpk, bcat, hqg, hkT, vpk);
  layer_kernel<false><<<512, 256, 0, stream>>>(
      hqg, hkT, vpk, mask, w2hg, be2, wopk, bo, og, oB,
      wcatpk + 49152, bcat + 384,
      hqg + 524288, hkT + 524288, vpk + 1048576, nullptr);
  layer_kernel<false><<<512, 256, 0, stream>>>(
      hqg + 524288, hkT + 524288, vpk + 1048576, mask, w2hg + 64, be2 + 1,
      wopk + 16384, bo + 128, og + 128, oB + 128,
      wcatpk + 2 * 49152, bcat + 2 * 384,
      hqg, hkT, vpk, nullptr);
  layer_kernel<true><<<512, 256, 0, stream>>>(
      hqg, hkT, vpk, mask, w2hg + 128, be2 + 2,
      wopk + 2 * 16384, bo + 256, og + 256, oB + 256,
      nullptr, nullptr, nullptr, nullptr, nullptr, poolp);
  dec_kernel<<<128, 256, 0, stream>>>(bf, poolp, mask, dW1, db1, dg1, dB1,
                                      dW2, db2, dg2, dB2, dW3, db3, out);
}